// Round 12
// baseline (1672.698 us; speedup 1.0000x reference)
//
#include <hip/hip_runtime.h>
#include <hip/hip_bf16.h>
#include <hip/hip_fp16.h>
#include <math.h>

#define BB 64
#define SS 512
#define TT 48
#define EE 300
#define EP 320   // E padded (160 k-pairs)
#define KP 160   // k-pairs per row
#define HH 256
#define G4 1024  // 4*H
#define NG 2048  // both directions
#define NEGV -10000.0f
#define SWQ (0.30f / 127.0f)   // Whh i8 scale

// k_lstm i8 weights: [dir][p<64][t<1024] uint. Thread t (unit G=t>>2, lane
// r=t&3) pins all 64: p = m*16+pq -> col 4G+m, k0 = 64r+4pq. 256 KB/dir =
// 64 VGPRs/thread at 1024 threads. NO LDS weights.
#define NWVN 131072   // 2*64*1024 uints

// DPP ctrls: quad_perm xor1=0xB1, xor2=0x4E; row_shr:4=0x114, row_shr:8=0x118
#define DPP0(x, ctrl) __builtin_amdgcn_update_dpp(0, (int)(x), (ctrl), 0xf, 0xf, false)

__device__ __forceinline__ float sigf(float x) { return 1.0f / (1.0f + __expf(-x)); }
__device__ __forceinline__ float tanhf_(float x) {
    float e = __expf(2.0f * x);
    return 1.0f - 2.0f / (e + 1.0f);
}

__device__ __forceinline__ int dot4(unsigned int h, unsigned int w, int acc) {
#if __has_builtin(__builtin_amdgcn_sdot4)
    return __builtin_amdgcn_sdot4((int)h, (int)w, acc, false);
#else
    acc += (int)(signed char)(h)       * (int)(signed char)(w);
    acc += (int)(signed char)(h >> 8)  * (int)(signed char)(w >> 8);
    acc += (int)(signed char)(h >> 16) * (int)(signed char)(w >> 16);
    acc += (int)(signed char)(h >> 24) * (int)(signed char)(w >> 24);
    return acc;
#endif
}

__device__ __forceinline__ float dot2u(unsigned int h, unsigned int w, float acc) {
#if __has_builtin(__builtin_amdgcn_fdot2)
    typedef _Float16 h2v __attribute__((ext_vector_type(2)));
    union { unsigned int u; h2v v; } H, W;
    H.u = h; W.u = w;
    return __builtin_amdgcn_fdot2(H.v, W.v, acc, false);
#else
    __half2 hh = *(__half2*)&h, ww = *(__half2*)&w;
    float2 hf = __half22float2(hh), wf = __half22float2(ww);
    return acc + hf.x * wf.x + hf.y * wf.y;
#endif
}

__device__ __forceinline__ unsigned int packh2(float lo, float hi) {
    union { __half2 h; unsigned int u; } p;
    p.h = __floats2half2_rn(lo, hi);
    return p.u;
}

__device__ __forceinline__ unsigned int q8(float x) {
    int q = __float2int_rn(fminf(fmaxf(x, -127.0f), 127.0f));
    return (unsigned int)(q & 0xff);
}

// ---------------- prep ----------------
// Gate-interleaved col order: col c = 4j+qg <-> source row qg*256+j
// WIHTP: [160][2048] uint (fp16 k-pair, permuted cols, zero-padded K)
// BIAS:  [2048] fp32 (permuted)
// WVN:   [dir][64][1024] uint (i8x4 Whh; see k_lstm layout)
// WOTP2: [64][48] uint4 (fp16 k-pairs of W_out^T, kp4-major)
__global__ __launch_bounds__(256) void k_prep(
    const float* __restrict__ Whh_f, const float* __restrict__ Whh_b,
    const float* __restrict__ Wih_f, const float* __restrict__ Wih_b,
    const float* __restrict__ bih_f, const float* __restrict__ bhh_f,
    const float* __restrict__ bih_b, const float* __restrict__ bhh_b,
    const float* __restrict__ W_out,
    unsigned int* __restrict__ WIHTP, float* __restrict__ BIAS,
    unsigned int* __restrict__ WVN, unsigned int* __restrict__ WOTP2)
{
    int i = blockIdx.x * 256 + threadIdx.x;
    const int NWIHP = KP * NG;     // 327680
    if (i < NWIHP) {
        int kp = i >> 11, n = i & 2047; int d = n >> 10, c = n & 1023;
        int row = (c & 3) * 256 + (c >> 2);
        const float* w = d ? Wih_b : Wih_f;
        int k0 = 2 * kp, k1 = 2 * kp + 1;
        WIHTP[i] = packh2(k0 < EE ? w[row * EE + k0] : 0.0f,
                          k1 < EE ? w[row * EE + k1] : 0.0f);
        return;
    }
    i -= NWIHP;
    if (i < NG) {
        int d = i >> 10, c = i & 1023;
        int row = (c & 3) * 256 + (c >> 2);
        BIAS[i] = d ? (bih_b[row] + bhh_b[row]) : (bih_f[row] + bhh_f[row]);
        return;
    }
    i -= NG;
    if (i < NWVN) {
        int d = i >> 16, rem = i & 65535;
        int p = rem >> 10, t = rem & 1023;
        int m = p >> 4, pq = p & 15;
        int G = t >> 2, r = t & 3;
        int srcrow = m * 256 + G;            // col 4G+m -> gate m of unit G
        int k0 = 64 * r + 4 * pq;
        const float* W = d ? Whh_b : Whh_f;
        unsigned int v = 0;
        #pragma unroll
        for (int bb = 0; bb < 4; bb++)
            v |= q8(W[srcrow * HH + k0 + bb] * (1.0f / SWQ)) << (8 * bb);
        WVN[i] = v;
        return;
    }
    i -= NWVN;
    if (i < 48 * 256) {   // 12288 uints
        int u4 = i >> 2;
        int kp4 = u4 / 48, t = u4 % 48;
        int kp = kp4 * 4 + (i & 3);
        WOTP2[i] = packh2(W_out[t * 512 + 2 * kp], W_out[t * 512 + 2 * kp + 1]);
        return;
    }
}

// ---------------- embedding gather + concat + pad ----------------
__global__ __launch_bounds__(320) void k_embed(
    const int* __restrict__ wid, const int* __restrict__ fid, const int* __restrict__ pid,
    const float* __restrict__ ew, const float* __restrict__ ef, const float* __restrict__ ep,
    __half* __restrict__ X)
{
    int sb = blockIdx.x; int s = sb >> 6, b = sb & 63;
    int t = threadIdx.x;
    int w = wid[b * SS + s];
    int f = fid[b * SS + s];
    int p = pid[b * SS + s];
    float v;
    if (t < 200)      v = ew[w * 200 + t];
    else if (t < 250) v = ef[f * 50 + (t - 200)];
    else if (t < 300) v = ep[p * 50 + (t - 250)];
    else              v = 0.0f;
    X[(size_t)sb * EP + t] = __float2half(v);
}

// ---------------- input GEMM: 128x128 tile, 8x8 frag, fp16 dot2 ----------
__global__ __launch_bounds__(256) void k_gemm(
    const unsigned int* __restrict__ XP, const unsigned int* __restrict__ WP,
    const float* __restrict__ BIAS, __half* __restrict__ GX)
{
    __shared__ unsigned int Al[8][132];
    __shared__ unsigned int Bl[8][144];
    int tid = threadIdx.x;
    int tx = tid & 15, ty = tid >> 4;
    int m0 = blockIdx.y * 128, n0 = blockIdx.x * 128;
    int ar = tid >> 1, aq = tid & 1;
    int bkp = tid >> 5, bq = tid & 31;
    int bc8 = bq >> 1, bsub = (bq & 1) * 4;
    int bword = bc8 * 8 + (bc8 >> 2) * 4 + bsub;
    int rword = tx * 8 + (tx >> 2) * 4;
    float acc[8][8] = {};

    uint4 a_reg = *(const uint4*)(XP + (size_t)(m0 + ar) * KP + 4 * aq);
    uint4 b_reg = *(const uint4*)(WP + (size_t)bkp * NG + n0 + 4 * bq);
    for (int it = 0; it < 20; it++) {
        Al[4 * aq + 0][ar] = a_reg.x; Al[4 * aq + 1][ar] = a_reg.y;
        Al[4 * aq + 2][ar] = a_reg.z; Al[4 * aq + 3][ar] = a_reg.w;
        *(uint4*)&Bl[bkp][bword] = b_reg;
        __syncthreads();
        if (it + 1 < 20) {
            int kpn = (it + 1) * 8;
            a_reg = *(const uint4*)(XP + (size_t)(m0 + ar) * KP + kpn + 4 * aq);
            b_reg = *(const uint4*)(WP + (size_t)(kpn + bkp) * NG + n0 + 4 * bq);
        }
        #pragma unroll
        for (int kp = 0; kp < 8; kp++) {
            uint4 a0 = *(const uint4*)&Al[kp][ty * 8];
            uint4 a1 = *(const uint4*)&Al[kp][ty * 8 + 4];
            uint4 b0 = *(const uint4*)&Bl[kp][rword];
            uint4 b1 = *(const uint4*)&Bl[kp][rword + 4];
            unsigned int av[8] = { a0.x, a0.y, a0.z, a0.w, a1.x, a1.y, a1.z, a1.w };
            unsigned int bv[8] = { b0.x, b0.y, b0.z, b0.w, b1.x, b1.y, b1.z, b1.w };
            #pragma unroll
            for (int ii = 0; ii < 8; ii++)
                #pragma unroll
                for (int jj = 0; jj < 8; jj++)
                    acc[ii][jj] = dot2u(av[ii], bv[jj], acc[ii][jj]);
        }
        __syncthreads();
    }
    float4 bs0 = *(const float4*)(BIAS + n0 + tx * 8);
    float4 bs1 = *(const float4*)(BIAS + n0 + tx * 8 + 4);
    float bias[8] = { bs0.x, bs0.y, bs0.z, bs0.w, bs1.x, bs1.y, bs1.z, bs1.w };
    #pragma unroll
    for (int ii = 0; ii < 8; ii++) {
        union { uint4 u4; unsigned int u[4]; } o;
        #pragma unroll
        for (int jj = 0; jj < 4; jj++)
            o.u[jj] = packh2(acc[ii][2 * jj] + bias[2 * jj],
                             acc[ii][2 * jj + 1] + bias[2 * jj + 1]);
        *(uint4*)(GX + (size_t)(m0 + ty * 8 + ii) * NG + n0 + tx * 8) = o.u4;
    }
}

// ---------------- recurrent LSTM: full VGPR residency, 1024 thr ----------
// 128 wgs x 1024 thr (16 waves, 4/SIMD, 128-reg cap). Thread t: unit G=t>>2,
// quad-lane r=t&3 owns all 4 gate-cols of unit G for k in [64r,64r+64):
// 64 pinned weight uints. LDS holds ONLY the 256B h8 buffer (i8 h).
// Quad butterfly-sum -> every lane holds all 4 gate sums -> direct gates,
// quad-redundant c/h. h8 repack + HS pair-store via row_shr DPP.
__global__ __launch_bounds__(1024, 1) void k_lstm(
    const unsigned int* __restrict__ WVN, const __half* __restrict__ GX,
    const float* __restrict__ h0, const float* __restrict__ c0,
    __half* __restrict__ HS)
{
    __shared__ __align__(16) unsigned int h8[2][64];
    int wg = blockIdx.x; int dir = wg >> 6, b = wg & 63;
    int t = threadIdx.x;
    int G = t >> 2, r = t & 3;

    const unsigned int* wv = WVN + (size_t)dir * (64 * 1024);
    unsigned int WR[64];
    #pragma unroll
    for (int p = 0; p < 64; p++) {
        unsigned int tmp = wv[p * 1024 + t];
        asm volatile("v_mov_b32 %0, %1" : "=v"(WR[p]) : "v"(tmp));
    }

    size_t sbase = (size_t)dir * BB * HH + b * HH;
    float c = c0[sbase + G];                 // quad-redundant
    if (t < 64) {
        unsigned int v = 0;
        #pragma unroll
        for (int u = 0; u < 4; u++)
            v |= q8(h0[sbase + 4 * t + u] * (127.0f / 5.0f)) << (8 * u);
        h8[0][t] = v;
    }
    __syncthreads();

    const __half* gxbase = GX + (dir << 10);
    int s0 = dir ? (SS - 1) : 0;
    uint2 gx = *(const uint2*)(gxbase + (size_t)(s0 * BB + b) * NG + 4 * G);

    int cur = 0;
    for (int tt = 0; tt < SS; tt++) {
        int s  = dir ? (SS - 1 - tt) : tt;
        int tn = (tt + 1 < SS) ? (tt + 1) : tt;
        int sn = dir ? (SS - 1 - tn) : tn;
        uint2 gx_n = *(const uint2*)(gxbase + (size_t)(sn * BB + b) * NG + 4 * G);

        int acc0 = 0, acc1 = 0, acc2 = 0, acc3 = 0;
        const unsigned int* hb = &h8[cur][16 * r];
        #pragma unroll
        for (int p4 = 0; p4 < 4; p4++) {
            uint4 hq = *(const uint4*)&hb[4 * p4];
            unsigned int he[4] = { hq.x, hq.y, hq.z, hq.w };
            #pragma unroll
            for (int e = 0; e < 4; e++) {
                int pq = 4 * p4 + e;
                acc0 = dot4(he[e], WR[pq],      acc0);
                acc1 = dot4(he[e], WR[16 + pq], acc1);
                acc2 = dot4(he[e], WR[32 + pq], acc2);
                acc3 = dot4(he[e], WR[48 + pq], acc3);
            }
        }
        // quad butterfly-sum: all 4 lanes end with full sums of all 4 cols
        acc0 += DPP0(acc0, 0xB1); acc0 += DPP0(acc0, 0x4E);
        acc1 += DPP0(acc1, 0xB1); acc1 += DPP0(acc1, 0x4E);
        acc2 += DPP0(acc2, 0xB1); acc2 += DPP0(acc2, 0x4E);
        acc3 += DPP0(acc3, 0xB1); acc3 += DPP0(acc3, 0x4E);

        float st = SWQ * ((tt == 0) ? (5.0f / 127.0f) : (1.0f / 127.0f));
        __half2 g01 = *(__half2*)&gx.x;  float2 f01 = __half22float2(g01);
        __half2 g23 = *(__half2*)&gx.y;  float2 f23 = __half22float2(g23);
        float pi = f01.x + st * (float)acc0;
        float pf = f01.y + st * (float)acc1;
        float pg = f23.x + st * (float)acc2;
        float po = f23.y + st * (float)acc3;
        c = sigf(pf) * c + sigf(pi) * tanhf_(pg);
        float h = sigf(po) * tanhf_(c);

        // i8 h repack: units 4v..4v+3 live on lanes 16v..16v+15
        unsigned int hv = q8(h * 127.0f) << (8 * (G & 3));
        unsigned int sv = hv | (unsigned int)DPP0(hv, 0x114);   // row_shr:4
        sv |= (unsigned int)DPP0(sv, 0x118);                    // row_shr:8
        if ((t & 15) == 0) h8[cur ^ 1][t >> 4] = sv;

        // fp16 HS: lane t (t&7==0) packs h(G), h(G+1) [row_shr:4 in-row]
        float hnx = __int_as_float(DPP0(__float_as_int(h), 0x114));
        if ((t & 7) == 0)
            *(unsigned int*)(HS + (size_t)(s * BB + b) * 512 + (dir << 8) + (t >> 1))
                = packh2(h, hnx);

        __syncthreads();
        cur ^= 1;
        gx = gx_n;
    }
}

// ---------------- feats: fp16 dot2, coalesced W_out^T ---------------------
__global__ __launch_bounds__(384) void k_feats(
    const unsigned int* __restrict__ HSU, const uint4* __restrict__ W2,
    const float* __restrict__ b_out, float* __restrict__ F)
{
    __shared__ unsigned int rl_u[8 * 256];
    int sb0 = blockIdx.x * 8;
    int tid = threadIdx.x;
    for (int i = tid; i < 512; i += 384) {
        int row = i >> 6, u4c = i & 63;
        uint4 v = *(const uint4*)(HSU + (size_t)(sb0 + row) * 256 + u4c * 4);
        *(uint4*)&rl_u[row * 256 + u4c * 4] = v;
    }
    __syncthreads();
    int rr = tid / TT, t = tid % TT;
    float acc = b_out[t];
    #pragma unroll 8
    for (int kp4 = 0; kp4 < 64; kp4++) {
        uint4 ru = *(const uint4*)&rl_u[rr * 256 + kp4 * 4];
        uint4 wu = W2[kp4 * 48 + t];
        acc = dot2u(ru.x, wu.x, acc);
        acc = dot2u(ru.y, wu.y, acc);
        acc = dot2u(ru.z, wu.z, acc);
        acc = dot2u(ru.w, wu.w, acc);
    }
    F[(size_t)(sb0 + rr) * TT + t] = acc;
}

// ---------------- Viterbi: 1 wave/batch, no barriers, F prefetch ----------
__global__ __launch_bounds__(64) void k_viterbi(
    const float* __restrict__ F, const float* __restrict__ trans,
    float* __restrict__ out)
{
    int b = blockIdx.x;
    int tid = threadIdx.x;
    __shared__ float tl[TT * TT];
    __shared__ float fv[TT];
    __shared__ unsigned char bp[SS * TT];
    __shared__ unsigned char path[SS];
    for (int i = tid; i < TT * TT; i += 64) {
        int prev = i / TT, nx = i % TT;
        tl[i] = trans[nx * TT + prev];
    }
    if (tid < TT) fv[tid] = NEGV;
    float fcur = (tid < TT) ? F[(size_t)(0 * BB + b) * TT + tid] : 0.0f;
    for (int s = 0; s < SS; s++) {
        float fnext = (tid < TT && s + 1 < SS)
                    ? F[(size_t)((s + 1) * BB + b) * TT + tid] : 0.0f;
        if (tid < TT) {
            float best = -1e30f; int bi = 0;
            #pragma unroll 8
            for (int prev = 0; prev < TT; prev++) {
                float sc = fv[prev] + tl[prev * TT + tid];
                if (sc > best) { best = sc; bi = prev; }
            }
            bp[s * TT + tid] = (unsigned char)bi;
            fv[tid] = best + fcur;
        }
        fcur = fnext;
    }
    if (tid == 0) {
        float best = fv[0]; int bi = 0;
        for (int i = 1; i < TT; i++) if (fv[i] > best) { best = fv[i]; bi = i; }
        out[b] = best;
        int tag = bi;
        path[SS - 1] = (unsigned char)tag;
        for (int jj = SS - 2; jj >= 0; jj--) {
            tag = bp[(jj + 1) * TT + tag];
            path[jj] = (unsigned char)tag;
        }
    }
    for (int jj = tid; jj < SS; jj += 64)
        out[BB + (size_t)b * SS + jj] = (float)path[jj];
}

extern "C" void kernel_launch(void* const* d_in, const int* in_sizes, int n_in,
                              void* d_out, int out_size, void* d_ws, size_t ws_size,
                              hipStream_t stream) {
    const int*   wid    = (const int*)d_in[0];
    const int*   fid    = (const int*)d_in[1];
    const int*   pid    = (const int*)d_in[2];
    const float* ew     = (const float*)d_in[3];
    const float* ef     = (const float*)d_in[4];
    const float* epn    = (const float*)d_in[5];
    const float* Wih_f  = (const float*)d_in[6];
    const float* Whh_f  = (const float*)d_in[7];
    const float* bih_f  = (const float*)d_in[8];
    const float* bhh_f  = (const float*)d_in[9];
    const float* Wih_b  = (const float*)d_in[10];
    const float* Whh_b  = (const float*)d_in[11];
    const float* bih_b  = (const float*)d_in[12];
    const float* bhh_b  = (const float*)d_in[13];
    const float* h0     = (const float*)d_in[14];
    const float* c0     = (const float*)d_in[15];
    const float* W_out  = (const float*)d_in[16];
    const float* b_out  = (const float*)d_in[17];
    const float* trans  = (const float*)d_in[18];

    char* p = (char*)d_ws;
    auto alloc = [&](size_t bytes) { char* r = p; p += (bytes + 255) & ~(size_t)255; return r; };
    __half*       X      = (__half*)alloc((size_t)32768 * EP * 2);       //  21.0 MB
    __half*       GX     = (__half*)alloc((size_t)32768 * NG * 2);       // 134.2 MB
    __half*       HS     = (__half*)alloc((size_t)32768 * 512 * 2);      //  33.6 MB
    unsigned int* WVN    = (unsigned int*)alloc((size_t)NWVN * 4);       //  512 KB
    unsigned int* WIHTP  = (unsigned int*)alloc((size_t)KP * NG * 4);    //   1.3 MB
    float*        BIAS   = (float*)alloc((size_t)NG * 4);                //   8 KB
    unsigned int* WOTP2  = (unsigned int*)alloc((size_t)48 * 256 * 4);   //  48 KB
    float*        F      = (float*)alloc((size_t)32768 * TT * 4);        //   6.3 MB

    // k_prep elements: 327680 + 2048 + 131072 + 12288 = 473088
    k_prep<<<1848, 256, 0, stream>>>(Whh_f, Whh_b, Wih_f, Wih_b,
                                     bih_f, bhh_f, bih_b, bhh_b, W_out,
                                     WIHTP, BIAS, WVN, WOTP2);
    k_embed<<<32768, 320, 0, stream>>>(wid, fid, pid, ew, ef, epn, X);
    k_gemm<<<dim3(16, 256), 256, 0, stream>>>((const unsigned int*)X, WIHTP, BIAS, GX);
    k_lstm<<<128, 1024, 0, stream>>>(WVN, GX, h0, c0, HS);
    k_feats<<<4096, 384, 0, stream>>>((const unsigned int*)HS, (const uint4*)WOTP2, b_out, F);
    k_viterbi<<<64, 64, 0, stream>>>(F, trans, (float*)d_out);
}

// Round 13
// 1617.097 us; speedup vs baseline: 1.0344x; 1.0344x over previous
//
#include <hip/hip_runtime.h>
#include <hip/hip_bf16.h>
#include <hip/hip_fp16.h>
#include <math.h>

#define BB 64
#define SS 512
#define TT 48
#define EE 300
#define EP 320   // E padded (160 k-pairs)
#define KP 160   // k-pairs per row
#define HH 256
#define G4 1024  // 4*H
#define NG 2048  // both directions
#define NEGV -10000.0f
#define SWQ (0.30f / 127.0f)   // Whh i8 scale

// k_lstm i8 weights per dir: 128 uints/thread (16 cols x 8 k-quads)
//   planes 0..63  (cols 0..7)  -> VGPR pin (64 regs)  [proven r10/r11: granted 88, no spill]
//   planes 64..127 (cols 8..15) -> LDS 16 uint4-groups (128 KB)
#define NWV 65536    // 2*64*512 uints
#define NWL 65536    // 2*16*512*4 uints

// DPP: quad_perm xor1=0xB1, xor2=0x4E, rot[1,2,3,0]=0x39; row_half_mirror=0x141
#define DPP0(x, ctrl) __builtin_amdgcn_update_dpp(0, (int)(x), (ctrl), 0xf, 0xf, false)

__device__ __forceinline__ float sigf(float x) { return 1.0f / (1.0f + __expf(-x)); }
__device__ __forceinline__ float tanhf_(float x) {
    float e = __expf(2.0f * x);
    return 1.0f - 2.0f / (e + 1.0f);
}

__device__ __forceinline__ int dot4(unsigned int h, unsigned int w, int acc) {
#if __has_builtin(__builtin_amdgcn_sdot4)
    return __builtin_amdgcn_sdot4((int)h, (int)w, acc, false);
#else
    acc += (int)(signed char)(h)       * (int)(signed char)(w);
    acc += (int)(signed char)(h >> 8)  * (int)(signed char)(w >> 8);
    acc += (int)(signed char)(h >> 16) * (int)(signed char)(w >> 16);
    acc += (int)(signed char)(h >> 24) * (int)(signed char)(w >> 24);
    return acc;
#endif
}

__device__ __forceinline__ float dot2u(unsigned int h, unsigned int w, float acc) {
#if __has_builtin(__builtin_amdgcn_fdot2)
    typedef _Float16 h2v __attribute__((ext_vector_type(2)));
    union { unsigned int u; h2v v; } H, W;
    H.u = h; W.u = w;
    return __builtin_amdgcn_fdot2(H.v, W.v, acc, false);
#else
    __half2 hh = *(__half2*)&h, ww = *(__half2*)&w;
    float2 hf = __half22float2(hh), wf = __half22float2(ww);
    return acc + hf.x * wf.x + hf.y * wf.y;
#endif
}

__device__ __forceinline__ unsigned int packh2(float lo, float hi) {
    union { __half2 h; unsigned int u; } p;
    p.h = __floats2half2_rn(lo, hi);
    return p.u;
}

__device__ __forceinline__ unsigned int q8(float x) {
    int q = __float2int_rn(fminf(fmaxf(x, -127.0f), 127.0f));
    return (unsigned int)(q & 0xff);
}

// ---------------- prep ----------------
// Gate-interleaved col order: col c = 4j+qg <-> source row qg*256+j
// WIHTP: [160][2048] uint (fp16 k-pair, permuted cols, zero-padded K)
// BIAS:  [2048] fp32 (permuted)
// WV8:   [dir][64][512] uint (i8x4; plane p: lc=p>>3, kq=p&7)
// WL8:   [dir][16][512] uint4 (i8x4; group g: lc=8+(g>>1), kq=(g&1)*4+m)
// WOTP2: [64][48] uint4 (fp16 k-pairs of W_out^T, kp4-major for coalescing)
__global__ __launch_bounds__(256) void k_prep(
    const float* __restrict__ Whh_f, const float* __restrict__ Whh_b,
    const float* __restrict__ Wih_f, const float* __restrict__ Wih_b,
    const float* __restrict__ bih_f, const float* __restrict__ bhh_f,
    const float* __restrict__ bih_b, const float* __restrict__ bhh_b,
    const float* __restrict__ W_out,
    unsigned int* __restrict__ WIHTP, float* __restrict__ BIAS,
    unsigned int* __restrict__ WV8, unsigned int* __restrict__ WL8,
    unsigned int* __restrict__ WOTP2)
{
    int i = blockIdx.x * 256 + threadIdx.x;
    const int NWIHP = KP * NG;     // 327680
    if (i < NWIHP) {
        int kp = i >> 11, n = i & 2047; int d = n >> 10, c = n & 1023;
        int row = (c & 3) * 256 + (c >> 2);
        const float* w = d ? Wih_b : Wih_f;
        int k0 = 2 * kp, k1 = 2 * kp + 1;
        WIHTP[i] = packh2(k0 < EE ? w[row * EE + k0] : 0.0f,
                          k1 < EE ? w[row * EE + k1] : 0.0f);
        return;
    }
    i -= NWIHP;
    if (i < NG) {
        int d = i >> 10, c = i & 1023;
        int row = (c & 3) * 256 + (c >> 2);
        BIAS[i] = d ? (bih_b[row] + bhh_b[row]) : (bih_f[row] + bhh_f[row]);
        return;
    }
    i -= NG;
    if (i < NWV) {
        int d = i >> 15, rem = i & 32767;
        int p = rem >> 9, t = rem & 511;
        int G = t >> 3, r = t & 7;
        int lc = p >> 3, kq = p & 7;
        int col = 16 * G + lc;
        int row = (col & 3) * 256 + (col >> 2);
        int k0 = 32 * r + 4 * kq;
        const float* W = d ? Whh_b : Whh_f;
        unsigned int v = 0;
        #pragma unroll
        for (int bb = 0; bb < 4; bb++)
            v |= q8(W[row * HH + k0 + bb] * (1.0f / SWQ)) << (8 * bb);
        WV8[i] = v;
        return;
    }
    i -= NWV;
    if (i < NWL) {
        int d = i >> 15, rem = i & 32767;
        int g = rem >> 11, i3 = rem & 2047;
        int t = i3 >> 2, m = i3 & 3;
        int G = t >> 3, r = t & 7;
        int lc = 8 + (g >> 1), kq = (g & 1) * 4 + m;
        int col = 16 * G + lc;
        int row = (col & 3) * 256 + (col >> 2);
        int k0 = 32 * r + 4 * kq;
        const float* W = d ? Whh_b : Whh_f;
        unsigned int v = 0;
        #pragma unroll
        for (int bb = 0; bb < 4; bb++)
            v |= q8(W[row * HH + k0 + bb] * (1.0f / SWQ)) << (8 * bb);
        WL8[i] = v;
        return;
    }
    i -= NWL;
    if (i < 48 * 256) {   // 12288 uints
        int u4 = i >> 2;
        int kp4 = u4 / 48, t = u4 % 48;
        int kp = kp4 * 4 + (i & 3);
        WOTP2[i] = packh2(W_out[t * 512 + 2 * kp], W_out[t * 512 + 2 * kp + 1]);
        return;
    }
}

// ---------------- embedding gather: 2048 blocks x 16 sb-rows each --------
// (was 32768 tiny blocks -- dispatch-overhead-bound)
__global__ __launch_bounds__(320) void k_embed(
    const int* __restrict__ wid, const int* __restrict__ fid, const int* __restrict__ pid,
    const float* __restrict__ ew, const float* __restrict__ ef, const float* __restrict__ ep,
    __half* __restrict__ X)
{
    int t = threadIdx.x;
    int sb0 = blockIdx.x * 16;
    #pragma unroll 4
    for (int it = 0; it < 16; it++) {
        int sb = sb0 + it;
        int s = sb >> 6, b = sb & 63;
        int w = wid[b * SS + s];
        int f = fid[b * SS + s];
        int p = pid[b * SS + s];
        float v;
        if (t < 200)      v = ew[w * 200 + t];
        else if (t < 250) v = ef[f * 50 + (t - 200)];
        else if (t < 300) v = ep[p * 50 + (t - 250)];
        else              v = 0.0f;
        X[(size_t)sb * EP + t] = __float2half(v);
    }
}

// ---------------- input GEMM: 128x128 tile, 8x8 frag, fp16 dot2 ----------
__global__ __launch_bounds__(256) void k_gemm(
    const unsigned int* __restrict__ XP, const unsigned int* __restrict__ WP,
    const float* __restrict__ BIAS, __half* __restrict__ GX)
{
    __shared__ unsigned int Al[8][132];
    __shared__ unsigned int Bl[8][144];
    int tid = threadIdx.x;
    int tx = tid & 15, ty = tid >> 4;
    int m0 = blockIdx.y * 128, n0 = blockIdx.x * 128;
    int ar = tid >> 1, aq = tid & 1;
    int bkp = tid >> 5, bq = tid & 31;
    int bc8 = bq >> 1, bsub = (bq & 1) * 4;
    int bword = bc8 * 8 + (bc8 >> 2) * 4 + bsub;
    int rword = tx * 8 + (tx >> 2) * 4;
    float acc[8][8] = {};

    uint4 a_reg = *(const uint4*)(XP + (size_t)(m0 + ar) * KP + 4 * aq);
    uint4 b_reg = *(const uint4*)(WP + (size_t)bkp * NG + n0 + 4 * bq);
    for (int it = 0; it < 20; it++) {
        Al[4 * aq + 0][ar] = a_reg.x; Al[4 * aq + 1][ar] = a_reg.y;
        Al[4 * aq + 2][ar] = a_reg.z; Al[4 * aq + 3][ar] = a_reg.w;
        *(uint4*)&Bl[bkp][bword] = b_reg;
        __syncthreads();
        if (it + 1 < 20) {
            int kpn = (it + 1) * 8;
            a_reg = *(const uint4*)(XP + (size_t)(m0 + ar) * KP + kpn + 4 * aq);
            b_reg = *(const uint4*)(WP + (size_t)(kpn + bkp) * NG + n0 + 4 * bq);
        }
        #pragma unroll
        for (int kp = 0; kp < 8; kp++) {
            uint4 a0 = *(const uint4*)&Al[kp][ty * 8];
            uint4 a1 = *(const uint4*)&Al[kp][ty * 8 + 4];
            uint4 b0 = *(const uint4*)&Bl[kp][rword];
            uint4 b1 = *(const uint4*)&Bl[kp][rword + 4];
            unsigned int av[8] = { a0.x, a0.y, a0.z, a0.w, a1.x, a1.y, a1.z, a1.w };
            unsigned int bv[8] = { b0.x, b0.y, b0.z, b0.w, b1.x, b1.y, b1.z, b1.w };
            #pragma unroll
            for (int ii = 0; ii < 8; ii++)
                #pragma unroll
                for (int jj = 0; jj < 8; jj++)
                    acc[ii][jj] = dot2u(av[ii], bv[jj], acc[ii][jj]);
        }
        __syncthreads();
    }
    float4 bs0 = *(const float4*)(BIAS + n0 + tx * 8);
    float4 bs1 = *(const float4*)(BIAS + n0 + tx * 8 + 4);
    float bias[8] = { bs0.x, bs0.y, bs0.z, bs0.w, bs1.x, bs1.y, bs1.z, bs1.w };
    #pragma unroll
    for (int ii = 0; ii < 8; ii++) {
        union { uint4 u4; unsigned int u[4]; } o;
        #pragma unroll
        for (int jj = 0; jj < 4; jj++)
            o.u[jj] = packh2(acc[ii][2 * jj] + bias[2 * jj],
                             acc[ii][2 * jj + 1] + bias[2 * jj + 1]);
        *(uint4*)(GX + (size_t)(m0 + ty * 8 + ii) * NG + n0 + tx * 8) = o.u4;
    }
}

// ---------------- recurrent LSTM: i8 resident, DPP reduce (r11 proven) ---
// 128 wgs x 512 thr. Octet G=t>>3 owns cols [16G,16G+16); lane r=t&7 owns
// k in [32r,32r+32). 64 weight-uints pinned in VGPRs + 64 in LDS (128 KB).
__global__ __launch_bounds__(512, 1) void k_lstm(
    const unsigned int* __restrict__ WV8, const uint4* __restrict__ WL8,
    const __half* __restrict__ GX, const float* __restrict__ h0,
    const float* __restrict__ c0, __half* __restrict__ HS)
{
    __shared__ uint4 LW[16 * 512];          // 128 KB i8 weights
    __shared__ unsigned int h8[2][64];      // packed i8 h
    int wg = blockIdx.x; int dir = wg >> 6, b = wg & 63;
    int t = threadIdx.x;
    int G = t >> 3, r = t & 7, rp = r & 3;

    const uint4* wl = WL8 + (size_t)dir * (16 * 512);
    #pragma unroll
    for (int g = 0; g < 16; g++) LW[g * 512 + t] = wl[g * 512 + t];

    const unsigned int* wv = WV8 + (size_t)dir * (64 * 512);
    unsigned int WR[64];
    #pragma unroll
    for (int p = 0; p < 64; p++) {
        unsigned int tmp = wv[p * 512 + t];
        asm volatile("v_mov_b32 %0, %1" : "=v"(WR[p]) : "v"(tmp));
    }

    size_t sbase = (size_t)dir * BB * HH + b * HH;
    float c = c0[sbase + 4 * G + rp];
    if (t < 64) {
        unsigned int v = 0;
        #pragma unroll
        for (int u = 0; u < 4; u++)
            v |= q8(h0[sbase + 4 * t + u] * (127.0f / 5.0f)) << (8 * u);
        h8[0][t] = v;
    }
    __syncthreads();

    const __half* gxbase = GX + (dir << 10);
    int s0 = dir ? (SS - 1) : 0;
    int unit = 4 * G + rp;
    uint2 gx = *(const uint2*)(gxbase + (size_t)(s0 * BB + b) * NG + 4 * unit);

    int cur = 0;
    for (int tt = 0; tt < SS; tt++) {
        int s  = dir ? (SS - 1 - tt) : tt;
        int tn = (tt + 1 < SS) ? (tt + 1) : tt;
        int sn = dir ? (SS - 1 - tn) : tn;
        uint2 gx_n = *(const uint2*)(gxbase + (size_t)(sn * BB + b) * NG + 4 * unit);

        uint4 hA = *(const uint4*)&h8[cur][8 * r];
        uint4 hB = *(const uint4*)&h8[cur][8 * r + 4];
        unsigned int hr[8] = { hA.x, hA.y, hA.z, hA.w, hB.x, hB.y, hB.z, hB.w };

        int acc[16];
        #pragma unroll
        for (int m = 0; m < 16; m++) acc[m] = 0;
        #pragma unroll
        for (int p = 0; p < 64; p++)
            acc[p >> 3] = dot4(hr[p & 7], WR[p], acc[p >> 3]);
        #pragma unroll
        for (int g = 0; g < 16; g++) {
            uint4 w = LW[g * 512 + t];
            const int lc = 8 + (g >> 1), kq0 = (g & 1) * 4;
            acc[lc] = dot4(hr[kq0 + 0], w.x, acc[lc]);
            acc[lc] = dot4(hr[kq0 + 1], w.y, acc[lc]);
            acc[lc] = dot4(hr[kq0 + 2], w.z, acc[lc]);
            acc[lc] = dot4(hr[kq0 + 3], w.w, acc[lc]);
        }

        // stage A: fold pairs r <-> 7-r (row_half_mirror)
        #pragma unroll
        for (int m = 0; m < 16; m++) acc[m] += DPP0(acc[m], 0x141);
        // stage B (xor2 quad_perm): keep 8 cols
        bool keep2 = (r & 2) == 0;
        int b8v[8];
        #pragma unroll
        for (int m = 0; m < 8; m++) {
            int send = keep2 ? acc[8 + m] : acc[m];
            int got  = DPP0(send, 0x4E);
            b8v[m] = (keep2 ? acc[m] : acc[8 + m]) + got;
        }
        // stage C (xor1): lane r holds cols 4(r&3)..+3
        bool keep1 = (r & 1) == 0;
        int f4v[4];
        #pragma unroll
        for (int m = 0; m < 4; m++) {
            int send = keep1 ? b8v[4 + m] : b8v[m];
            int got  = DPP0(send, 0xB1);
            f4v[m] = (keep1 ? b8v[m] : b8v[4 + m]) + got;
        }

        float st = SWQ * ((tt == 0) ? (5.0f / 127.0f) : (1.0f / 127.0f));
        __half2 g01 = *(__half2*)&gx.x;  float2 f01 = __half22float2(g01);
        __half2 g23 = *(__half2*)&gx.y;  float2 f23 = __half22float2(g23);
        float pi = f01.x + st * (float)f4v[0];
        float pf = f01.y + st * (float)f4v[1];
        float pg = f23.x + st * (float)f4v[2];
        float po = f23.y + st * (float)f4v[3];
        c = sigf(pf) * c + sigf(pi) * tanhf_(pg);
        float h = sigf(po) * tanhf_(c);

        unsigned int hv = q8(h * 127.0f) << (8 * rp);
        hv |= (unsigned int)DPP0(hv, 0xB1);
        hv |= (unsigned int)DPP0(hv, 0x4E);
        if (r == 0) h8[cur ^ 1][G] = hv;

        float hnx = __int_as_float(DPP0(__float_as_int(h), 0x39));
        if (r == 0 || r == 2)
            *(unsigned int*)(HS + (size_t)(s * BB + b) * 512 + (dir << 8) + 4 * G + r)
                = packh2(h, hnx);

        __syncthreads();
        cur ^= 1;
        gx = gx_n;
    }
}

// ---------------- feats: fp16 dot2, coalesced W_out^T ---------------------
__global__ __launch_bounds__(384) void k_feats(
    const unsigned int* __restrict__ HSU, const uint4* __restrict__ W2,
    const float* __restrict__ b_out, float* __restrict__ F)
{
    __shared__ unsigned int rl_u[8 * 256];
    int sb0 = blockIdx.x * 8;
    int tid = threadIdx.x;
    for (int i = tid; i < 512; i += 384) {
        int row = i >> 6, u4c = i & 63;
        uint4 v = *(const uint4*)(HSU + (size_t)(sb0 + row) * 256 + u4c * 4);
        *(uint4*)&rl_u[row * 256 + u4c * 4] = v;
    }
    __syncthreads();
    int rr = tid / TT, t = tid % TT;
    float acc = b_out[t];
    #pragma unroll 8
    for (int kp4 = 0; kp4 < 64; kp4++) {
        uint4 ru = *(const uint4*)&rl_u[rr * 256 + kp4 * 4];
        uint4 wu = W2[kp4 * 48 + t];
        acc = dot2u(ru.x, wu.x, acc);
        acc = dot2u(ru.y, wu.y, acc);
        acc = dot2u(ru.z, wu.z, acc);
        acc = dot2u(ru.w, wu.w, acc);
    }
    F[(size_t)(sb0 + rr) * TT + t] = acc;
}

// ---------------- Viterbi: 1 wave/batch, no barriers, F prefetch ----------
__global__ __launch_bounds__(64) void k_viterbi(
    const float* __restrict__ F, const float* __restrict__ trans,
    float* __restrict__ out)
{
    int b = blockIdx.x;
    int tid = threadIdx.x;
    __shared__ float tl[TT * TT];
    __shared__ float fv[TT];
    __shared__ unsigned char bp[SS * TT];
    __shared__ unsigned char path[SS];
    for (int i = tid; i < TT * TT; i += 64) {
        int prev = i / TT, nx = i % TT;
        tl[i] = trans[nx * TT + prev];
    }
    if (tid < TT) fv[tid] = NEGV;
    float fcur = (tid < TT) ? F[(size_t)(0 * BB + b) * TT + tid] : 0.0f;
    for (int s = 0; s < SS; s++) {
        float fnext = (tid < TT && s + 1 < SS)
                    ? F[(size_t)((s + 1) * BB + b) * TT + tid] : 0.0f;
        if (tid < TT) {
            float best = -1e30f; int bi = 0;
            #pragma unroll 8
            for (int prev = 0; prev < TT; prev++) {
                float sc = fv[prev] + tl[prev * TT + tid];
                if (sc > best) { best = sc; bi = prev; }
            }
            bp[s * TT + tid] = (unsigned char)bi;
            fv[tid] = best + fcur;
        }
        fcur = fnext;
    }
    if (tid == 0) {
        float best = fv[0]; int bi = 0;
        for (int i = 1; i < TT; i++) if (fv[i] > best) { best = fv[i]; bi = i; }
        out[b] = best;
        int tag = bi;
        path[SS - 1] = (unsigned char)tag;
        for (int jj = SS - 2; jj >= 0; jj--) {
            tag = bp[(jj + 1) * TT + tag];
            path[jj] = (unsigned char)tag;
        }
    }
    for (int jj = tid; jj < SS; jj += 64)
        out[BB + (size_t)b * SS + jj] = (float)path[jj];
}

extern "C" void kernel_launch(void* const* d_in, const int* in_sizes, int n_in,
                              void* d_out, int out_size, void* d_ws, size_t ws_size,
                              hipStream_t stream) {
    const int*   wid    = (const int*)d_in[0];
    const int*   fid    = (const int*)d_in[1];
    const int*   pid    = (const int*)d_in[2];
    const float* ew     = (const float*)d_in[3];
    const float* ef     = (const float*)d_in[4];
    const float* epn    = (const float*)d_in[5];
    const float* Wih_f  = (const float*)d_in[6];
    const float* Whh_f  = (const float*)d_in[7];
    const float* bih_f  = (const float*)d_in[8];
    const float* bhh_f  = (const float*)d_in[9];
    const float* Wih_b  = (const float*)d_in[10];
    const float* Whh_b  = (const float*)d_in[11];
    const float* bih_b  = (const float*)d_in[12];
    const float* bhh_b  = (const float*)d_in[13];
    const float* h0     = (const float*)d_in[14];
    const float* c0     = (const float*)d_in[15];
    const float* W_out  = (const float*)d_in[16];
    const float* b_out  = (const float*)d_in[17];
    const float* trans  = (const float*)d_in[18];

    char* p = (char*)d_ws;
    auto alloc = [&](size_t bytes) { char* r = p; p += (bytes + 255) & ~(size_t)255; return r; };
    __half*       X      = (__half*)alloc((size_t)32768 * EP * 2);       //  21.0 MB
    __half*       GX     = (__half*)alloc((size_t)32768 * NG * 2);       // 134.2 MB
    __half*       HS     = (__half*)alloc((size_t)32768 * 512 * 2);      //  33.6 MB
    unsigned int* WV8    = (unsigned int*)alloc((size_t)NWV * 4);        //  256 KB
    unsigned int* WL8    = (unsigned int*)alloc((size_t)NWL * 4);        //  256 KB
    unsigned int* WIHTP  = (unsigned int*)alloc((size_t)KP * NG * 4);    //   1.3 MB
    float*        BIAS   = (float*)alloc((size_t)NG * 4);                //   8 KB
    unsigned int* WOTP2  = (unsigned int*)alloc((size_t)48 * 256 * 4);   //  48 KB
    float*        F      = (float*)alloc((size_t)32768 * TT * 4);        //   6.3 MB

    // k_prep elements: 327680 + 2048 + 65536 + 65536 + 12288 = 473088
    k_prep<<<1848, 256, 0, stream>>>(Whh_f, Whh_b, Wih_f, Wih_b,
                                     bih_f, bhh_f, bih_b, bhh_b, W_out,
                                     WIHTP, BIAS, WV8, WL8, WOTP2);
    k_embed<<<2048, 320, 0, stream>>>(wid, fid, pid, ew, ef, epn, X);
    k_gemm<<<dim3(16, 256), 256, 0, stream>>>((const unsigned int*)X, WIHTP, BIAS, GX);
    k_lstm<<<128, 512, 0, stream>>>(WV8, (const uint4*)WL8, GX, h0, c0, HS);
    k_feats<<<4096, 384, 0, stream>>>((const unsigned int*)HS, (const uint4*)WOTP2, b_out, F);
    k_viterbi<<<64, 64, 0, stream>>>(F, trans, (float*)d_out);
}

// Round 14
// 1463.674 us; speedup vs baseline: 1.1428x; 1.1048x over previous
//
#include <hip/hip_runtime.h>
#include <hip/hip_bf16.h>
#include <hip/hip_fp16.h>
#include <math.h>

#define BB 64
#define SS 512
#define TT 48
#define EE 300
#define EP 320   // E padded
#define HH 256
#define G4 1024  // 4*H
#define NG 2048  // both directions
#define NEGV -10000.0f
#define SWQ (0.30f / 127.0f)   // Whh i8 scale

// k_lstm i8 weights per dir: 128 uints/thread (16 cols x 8 k-quads)
//   planes 0..63  (cols 0..7)  -> VGPR pin (64 regs)  [proven: granted 88, no spill]
//   planes 64..127 (cols 8..15) -> LDS 16 uint4-groups (128 KB)
#define NWV 65536    // 2*64*512 uints
#define NWL 65536    // 2*16*512*4 uints

// DPP: quad_perm xor1=0xB1, xor2=0x4E, rot[1,2,3,0]=0x39; row_half_mirror=0x141
#define DPP0(x, ctrl) __builtin_amdgcn_update_dpp(0, (int)(x), (ctrl), 0xf, 0xf, false)

typedef _Float16 f16x8 __attribute__((ext_vector_type(8)));
typedef float f32x4 __attribute__((ext_vector_type(4)));

__device__ __forceinline__ float sigf(float x) { return 1.0f / (1.0f + __expf(-x)); }
__device__ __forceinline__ float tanhf_(float x) {
    float e = __expf(2.0f * x);
    return 1.0f - 2.0f / (e + 1.0f);
}

__device__ __forceinline__ int dot4(unsigned int h, unsigned int w, int acc) {
#if __has_builtin(__builtin_amdgcn_sdot4)
    return __builtin_amdgcn_sdot4((int)h, (int)w, acc, false);
#else
    acc += (int)(signed char)(h)       * (int)(signed char)(w);
    acc += (int)(signed char)(h >> 8)  * (int)(signed char)(w >> 8);
    acc += (int)(signed char)(h >> 16) * (int)(signed char)(w >> 16);
    acc += (int)(signed char)(h >> 24) * (int)(signed char)(w >> 24);
    return acc;
#endif
}

__device__ __forceinline__ float dot2u(unsigned int h, unsigned int w, float acc) {
#if __has_builtin(__builtin_amdgcn_fdot2)
    typedef _Float16 h2v __attribute__((ext_vector_type(2)));
    union { unsigned int u; h2v v; } H, W;
    H.u = h; W.u = w;
    return __builtin_amdgcn_fdot2(H.v, W.v, acc, false);
#else
    __half2 hh = *(__half2*)&h, ww = *(__half2*)&w;
    float2 hf = __half22float2(hh), wf = __half22float2(ww);
    return acc + hf.x * wf.x + hf.y * wf.y;
#endif
}

__device__ __forceinline__ unsigned int packh2(float lo, float hi) {
    union { __half2 h; unsigned int u; } p;
    p.h = __floats2half2_rn(lo, hi);
    return p.u;
}

__device__ __forceinline__ unsigned int q8(float x) {
    int q = __float2int_rn(fminf(fmaxf(x, -127.0f), 127.0f));
    return (unsigned int)(q & 0xff);
}

// ---------------- prep ----------------
// Gate-interleaved col order: col c = 4j+qg <-> source row qg*256+j
// WIHT2: [2048 n][320 k] fp16 (n-major WihT, permuted cols, zero-padded K)
// BIAS:  [2048] fp32 (permuted)
// WV8:   [dir][64][512] uint (i8x4; plane p: lc=p>>3, kq=p&7)
// WL8:   [dir][16][512] uint4 (i8x4; group g: lc=8+(g>>1), kq=(g&1)*4+m)
// WOTP2: [64][48] uint4 (fp16 k-pairs of W_out^T, kp4-major)
__global__ __launch_bounds__(256) void k_prep(
    const float* __restrict__ Whh_f, const float* __restrict__ Whh_b,
    const float* __restrict__ Wih_f, const float* __restrict__ Wih_b,
    const float* __restrict__ bih_f, const float* __restrict__ bhh_f,
    const float* __restrict__ bih_b, const float* __restrict__ bhh_b,
    const float* __restrict__ W_out,
    __half* __restrict__ WIHT2, float* __restrict__ BIAS,
    unsigned int* __restrict__ WV8, unsigned int* __restrict__ WL8,
    unsigned int* __restrict__ WOTP2)
{
    int i = blockIdx.x * 256 + threadIdx.x;
    const int NWIHT2 = NG * EP;    // 655360
    if (i < NWIHT2) {
        int n = i / EP, k = i % EP;
        int d = n >> 10, c = n & 1023;
        int row = (c & 3) * 256 + (c >> 2);
        const float* w = d ? Wih_b : Wih_f;
        WIHT2[i] = __float2half(k < EE ? w[row * EE + k] : 0.0f);
        return;
    }
    i -= NWIHT2;
    if (i < NG) {
        int d = i >> 10, c = i & 1023;
        int row = (c & 3) * 256 + (c >> 2);
        BIAS[i] = d ? (bih_b[row] + bhh_b[row]) : (bih_f[row] + bhh_f[row]);
        return;
    }
    i -= NG;
    if (i < NWV) {
        int d = i >> 15, rem = i & 32767;
        int p = rem >> 9, t = rem & 511;
        int G = t >> 3, r = t & 7;
        int lc = p >> 3, kq = p & 7;
        int col = 16 * G + lc;
        int row = (col & 3) * 256 + (col >> 2);
        int k0 = 32 * r + 4 * kq;
        const float* W = d ? Whh_b : Whh_f;
        unsigned int v = 0;
        #pragma unroll
        for (int bb = 0; bb < 4; bb++)
            v |= q8(W[row * HH + k0 + bb] * (1.0f / SWQ)) << (8 * bb);
        WV8[i] = v;
        return;
    }
    i -= NWV;
    if (i < NWL) {
        int d = i >> 15, rem = i & 32767;
        int g = rem >> 11, i3 = rem & 2047;
        int t = i3 >> 2, m = i3 & 3;
        int G = t >> 3, r = t & 7;
        int lc = 8 + (g >> 1), kq = (g & 1) * 4 + m;
        int col = 16 * G + lc;
        int row = (col & 3) * 256 + (col >> 2);
        int k0 = 32 * r + 4 * kq;
        const float* W = d ? Whh_b : Whh_f;
        unsigned int v = 0;
        #pragma unroll
        for (int bb = 0; bb < 4; bb++)
            v |= q8(W[row * HH + k0 + bb] * (1.0f / SWQ)) << (8 * bb);
        WL8[i] = v;
        return;
    }
    i -= NWL;
    if (i < 48 * 256) {   // 12288 uints
        int u4 = i >> 2;
        int kp4 = u4 / 48, t = u4 % 48;
        int kp = kp4 * 4 + (i & 3);
        WOTP2[i] = packh2(W_out[t * 512 + 2 * kp], W_out[t * 512 + 2 * kp + 1]);
        return;
    }
}

// ---------------- embedding gather: 2048 blocks x 16 sb-rows each --------
__global__ __launch_bounds__(320) void k_embed(
    const int* __restrict__ wid, const int* __restrict__ fid, const int* __restrict__ pid,
    const float* __restrict__ ew, const float* __restrict__ ef, const float* __restrict__ ep,
    __half* __restrict__ X)
{
    int t = threadIdx.x;
    int sb0 = blockIdx.x * 16;
    #pragma unroll 4
    for (int it = 0; it < 16; it++) {
        int sb = sb0 + it;
        int s = sb >> 6, b = sb & 63;
        int w = wid[b * SS + s];
        int f = fid[b * SS + s];
        int p = pid[b * SS + s];
        float v;
        if (t < 200)      v = ew[w * 200 + t];
        else if (t < 250) v = ef[f * 50 + (t - 200)];
        else if (t < 300) v = ep[p * 50 + (t - 250)];
        else              v = 0.0f;
        X[(size_t)sb * EP + t] = __float2half(v);
    }
}

// ---------------- input GEMM: MFMA 16x16x32 f16, global-direct frags -----
// grid (8, 512), 256 thr = 4 waves; wave computes 64(m) x 64(n) tile.
// A from X[m][k] row-major; B from WIHT2[n][k] n-major (both 16B/lane
// gathers). A/B use the same (lane-group,elem)->k storage mapping, so any
// k-permutation vs the HW mapping cancels in the contraction. C/D mapping
// (HW-verified): col=lane&15, row=(lane>>4)*4+reg.
__global__ __launch_bounds__(256) void k_gemm(
    const __half* __restrict__ X, const __half* __restrict__ WT,
    const float* __restrict__ BIAS, __half* __restrict__ GX)
{
    int tid = threadIdx.x;
    int l = tid & 63, wn = tid >> 6;
    int m0 = blockIdx.y * 64, nb = blockIdx.x * 256 + wn * 64;
    int lr = l & 15, lg = l >> 4;

    f32x4 acc[16];
    #pragma unroll
    for (int i = 0; i < 16; i++) acc[i] = (f32x4){0.0f, 0.0f, 0.0f, 0.0f};

    const __half* ab = X  + (size_t)(m0 + lr) * EP + lg * 8;
    const __half* bb = WT + (size_t)(nb + lr) * EP + lg * 8;
    for (int kc = 0; kc < 10; kc++) {
        f16x8 af[4], bf[4];
        #pragma unroll
        for (int mi = 0; mi < 4; mi++)
            af[mi] = *(const f16x8*)(ab + (size_t)mi * 16 * EP + kc * 32);
        #pragma unroll
        for (int nj = 0; nj < 4; nj++)
            bf[nj] = *(const f16x8*)(bb + (size_t)nj * 16 * EP + kc * 32);
        #pragma unroll
        for (int mi = 0; mi < 4; mi++)
            #pragma unroll
            for (int nj = 0; nj < 4; nj++)
                acc[mi * 4 + nj] = __builtin_amdgcn_mfma_f32_16x16x32_f16(
                    af[mi], bf[nj], acc[mi * 4 + nj], 0, 0, 0);
    }
    #pragma unroll
    for (int nj = 0; nj < 4; nj++) {
        float bias = BIAS[nb + nj * 16 + lr];
        #pragma unroll
        for (int mi = 0; mi < 4; mi++) {
            f32x4 a = acc[mi * 4 + nj];
            #pragma unroll
            for (int v = 0; v < 4; v++) {
                int m = m0 + mi * 16 + lg * 4 + v;
                GX[(size_t)m * NG + nb + nj * 16 + lr] = __float2half(a[v] + bias);
            }
        }
    }
}

// ---------------- recurrent LSTM: i8 resident, DPP reduce (r11 proven) ---
// 128 wgs x 512 thr. Octet G=t>>3 owns cols [16G,16G+16); lane r=t&7 owns
// k in [32r,32r+32). 64 weight-uints pinned in VGPRs + 64 in LDS (128 KB).
__global__ __launch_bounds__(512, 1) void k_lstm(
    const unsigned int* __restrict__ WV8, const uint4* __restrict__ WL8,
    const __half* __restrict__ GX, const float* __restrict__ h0,
    const float* __restrict__ c0, __half* __restrict__ HS)
{
    __shared__ uint4 LW[16 * 512];          // 128 KB i8 weights
    __shared__ unsigned int h8[2][64];      // packed i8 h
    int wg = blockIdx.x; int dir = wg >> 6, b = wg & 63;
    int t = threadIdx.x;
    int G = t >> 3, r = t & 7, rp = r & 3;

    const uint4* wl = WL8 + (size_t)dir * (16 * 512);
    #pragma unroll
    for (int g = 0; g < 16; g++) LW[g * 512 + t] = wl[g * 512 + t];

    const unsigned int* wv = WV8 + (size_t)dir * (64 * 512);
    unsigned int WR[64];
    #pragma unroll
    for (int p = 0; p < 64; p++) {
        unsigned int tmp = wv[p * 512 + t];
        asm volatile("v_mov_b32 %0, %1" : "=v"(WR[p]) : "v"(tmp));
    }

    size_t sbase = (size_t)dir * BB * HH + b * HH;
    float c = c0[sbase + 4 * G + rp];
    if (t < 64) {
        unsigned int v = 0;
        #pragma unroll
        for (int u = 0; u < 4; u++)
            v |= q8(h0[sbase + 4 * t + u] * (127.0f / 5.0f)) << (8 * u);
        h8[0][t] = v;
    }
    __syncthreads();

    const __half* gxbase = GX + (dir << 10);
    int s0 = dir ? (SS - 1) : 0;
    int unit = 4 * G + rp;
    uint2 gx = *(const uint2*)(gxbase + (size_t)(s0 * BB + b) * NG + 4 * unit);

    int cur = 0;
    for (int tt = 0; tt < SS; tt++) {
        int s  = dir ? (SS - 1 - tt) : tt;
        int tn = (tt + 1 < SS) ? (tt + 1) : tt;
        int sn = dir ? (SS - 1 - tn) : tn;
        uint2 gx_n = *(const uint2*)(gxbase + (size_t)(sn * BB + b) * NG + 4 * unit);

        uint4 hA = *(const uint4*)&h8[cur][8 * r];
        uint4 hB = *(const uint4*)&h8[cur][8 * r + 4];
        unsigned int hr[8] = { hA.x, hA.y, hA.z, hA.w, hB.x, hB.y, hB.z, hB.w };

        int acc[16];
        #pragma unroll
        for (int m = 0; m < 16; m++) acc[m] = 0;
        #pragma unroll
        for (int p = 0; p < 64; p++)
            acc[p >> 3] = dot4(hr[p & 7], WR[p], acc[p >> 3]);
        #pragma unroll
        for (int g = 0; g < 16; g++) {
            uint4 w = LW[g * 512 + t];
            const int lc = 8 + (g >> 1), kq0 = (g & 1) * 4;
            acc[lc] = dot4(hr[kq0 + 0], w.x, acc[lc]);
            acc[lc] = dot4(hr[kq0 + 1], w.y, acc[lc]);
            acc[lc] = dot4(hr[kq0 + 2], w.z, acc[lc]);
            acc[lc] = dot4(hr[kq0 + 3], w.w, acc[lc]);
        }

        // stage A: fold pairs r <-> 7-r (row_half_mirror)
        #pragma unroll
        for (int m = 0; m < 16; m++) acc[m] += DPP0(acc[m], 0x141);
        // stage B (xor2 quad_perm): keep 8 cols
        bool keep2 = (r & 2) == 0;
        int b8v[8];
        #pragma unroll
        for (int m = 0; m < 8; m++) {
            int send = keep2 ? acc[8 + m] : acc[m];
            int got  = DPP0(send, 0x4E);
            b8v[m] = (keep2 ? acc[m] : acc[8 + m]) + got;
        }
        // stage C (xor1): lane r holds cols 4(r&3)..+3
        bool keep1 = (r & 1) == 0;
        int f4v[4];
        #pragma unroll
        for (int m = 0; m < 4; m++) {
            int send = keep1 ? b8v[4 + m] : b8v[m];
            int got  = DPP0(send, 0xB1);
            f4v[m] = (keep1 ? b8v[m] : b8v[4 + m]) + got;
        }

        float st = SWQ * ((tt == 0) ? (5.0f / 127.0f) : (1.0f / 127.0f));
        __half2 g01 = *(__half2*)&gx.x;  float2 f01 = __half22float2(g01);
        __half2 g23 = *(__half2*)&gx.y;  float2 f23 = __half22float2(g23);
        float pi = f01.x + st * (float)f4v[0];
        float pf = f01.y + st * (float)f4v[1];
        float pg = f23.x + st * (float)f4v[2];
        float po = f23.y + st * (float)f4v[3];
        c = sigf(pf) * c + sigf(pi) * tanhf_(pg);
        float h = sigf(po) * tanhf_(c);

        unsigned int hv = q8(h * 127.0f) << (8 * rp);
        hv |= (unsigned int)DPP0(hv, 0xB1);
        hv |= (unsigned int)DPP0(hv, 0x4E);
        if (r == 0) h8[cur ^ 1][G] = hv;

        float hnx = __int_as_float(DPP0(__float_as_int(h), 0x39));
        if (r == 0 || r == 2)
            *(unsigned int*)(HS + (size_t)(s * BB + b) * 512 + (dir << 8) + 4 * G + r)
                = packh2(h, hnx);

        __syncthreads();
        cur ^= 1;
        gx = gx_n;
    }
}

// ---------------- feats: fp16 dot2, coalesced W_out^T ---------------------
__global__ __launch_bounds__(384) void k_feats(
    const unsigned int* __restrict__ HSU, const uint4* __restrict__ W2,
    const float* __restrict__ b_out, float* __restrict__ F)
{
    __shared__ unsigned int rl_u[8 * 256];
    int sb0 = blockIdx.x * 8;
    int tid = threadIdx.x;
    for (int i = tid; i < 512; i += 384) {
        int row = i >> 6, u4c = i & 63;
        uint4 v = *(const uint4*)(HSU + (size_t)(sb0 + row) * 256 + u4c * 4);
        *(uint4*)&rl_u[row * 256 + u4c * 4] = v;
    }
    __syncthreads();
    int rr = tid / TT, t = tid % TT;
    float acc = b_out[t];
    #pragma unroll 8
    for (int kp4 = 0; kp4 < 64; kp4++) {
        uint4 ru = *(const uint4*)&rl_u[rr * 256 + kp4 * 4];
        uint4 wu = W2[kp4 * 48 + t];
        acc = dot2u(ru.x, wu.x, acc);
        acc = dot2u(ru.y, wu.y, acc);
        acc = dot2u(ru.z, wu.z, acc);
        acc = dot2u(ru.w, wu.w, acc);
    }
    F[(size_t)(sb0 + rr) * TT + t] = acc;
}

// ---------------- Viterbi: 1 wave/batch, no barriers, F prefetch ----------
__global__ __launch_bounds__(64) void k_viterbi(
    const float* __restrict__ F, const float* __restrict__ trans,
    float* __restrict__ out)
{
    int b = blockIdx.x;
    int tid = threadIdx.x;
    __shared__ float tl[TT * TT];
    __shared__ float fv[TT];
    __shared__ unsigned char bp[SS * TT];
    __shared__ unsigned char path[SS];
    for (int i = tid; i < TT * TT; i += 64) {
        int prev = i / TT, nx = i % TT;
        tl[i] = trans[nx * TT + prev];
    }
    if (tid < TT) fv[tid] = NEGV;
    float fcur = (tid < TT) ? F[(size_t)(0 * BB + b) * TT + tid] : 0.0f;
    for (int s = 0; s < SS; s++) {
        float fnext = (tid < TT && s + 1 < SS)
                    ? F[(size_t)((s + 1) * BB + b) * TT + tid] : 0.0f;
        if (tid < TT) {
            float best = -1e30f; int bi = 0;
            #pragma unroll 8
            for (int prev = 0; prev < TT; prev++) {
                float sc = fv[prev] + tl[prev * TT + tid];
                if (sc > best) { best = sc; bi = prev; }
            }
            bp[s * TT + tid] = (unsigned char)bi;
            fv[tid] = best + fcur;
        }
        fcur = fnext;
    }
    if (tid == 0) {
        float best = fv[0]; int bi = 0;
        for (int i = 1; i < TT; i++) if (fv[i] > best) { best = fv[i]; bi = i; }
        out[b] = best;
        int tag = bi;
        path[SS - 1] = (unsigned char)tag;
        for (int jj = SS - 2; jj >= 0; jj--) {
            tag = bp[(jj + 1) * TT + tag];
            path[jj] = (unsigned char)tag;
        }
    }
    for (int jj = tid; jj < SS; jj += 64)
        out[BB + (size_t)b * SS + jj] = (float)path[jj];
}

extern "C" void kernel_launch(void* const* d_in, const int* in_sizes, int n_in,
                              void* d_out, int out_size, void* d_ws, size_t ws_size,
                              hipStream_t stream) {
    const int*   wid    = (const int*)d_in[0];
    const int*   fid    = (const int*)d_in[1];
    const int*   pid    = (const int*)d_in[2];
    const float* ew     = (const float*)d_in[3];
    const float* ef     = (const float*)d_in[4];
    const float* epn    = (const float*)d_in[5];
    const float* Wih_f  = (const float*)d_in[6];
    const float* Whh_f  = (const float*)d_in[7];
    const float* bih_f  = (const float*)d_in[8];
    const float* bhh_f  = (const float*)d_in[9];
    const float* Wih_b  = (const float*)d_in[10];
    const float* Whh_b  = (const float*)d_in[11];
    const float* bih_b  = (const float*)d_in[12];
    const float* bhh_b  = (const float*)d_in[13];
    const float* h0     = (const float*)d_in[14];
    const float* c0     = (const float*)d_in[15];
    const float* W_out  = (const float*)d_in[16];
    const float* b_out  = (const float*)d_in[17];
    const float* trans  = (const float*)d_in[18];

    char* p = (char*)d_ws;
    auto alloc = [&](size_t bytes) { char* r = p; p += (bytes + 255) & ~(size_t)255; return r; };
    __half*       X      = (__half*)alloc((size_t)32768 * EP * 2);       //  21.0 MB
    __half*       GX     = (__half*)alloc((size_t)32768 * NG * 2);       // 134.2 MB
    __half*       HS     = (__half*)alloc((size_t)32768 * 512 * 2);      //  33.6 MB
    unsigned int* WV8    = (unsigned int*)alloc((size_t)NWV * 4);        //  256 KB
    unsigned int* WL8    = (unsigned int*)alloc((size_t)NWL * 4);        //  256 KB
    __half*       WIHT2  = (__half*)alloc((size_t)NG * EP * 2);          //   1.3 MB
    float*        BIAS   = (float*)alloc((size_t)NG * 4);                //   8 KB
    unsigned int* WOTP2  = (unsigned int*)alloc((size_t)48 * 256 * 4);   //  48 KB
    float*        F      = (float*)alloc((size_t)32768 * TT * 4);        //   6.3 MB

    // k_prep elements: 655360 + 2048 + 65536 + 65536 + 12288 = 800768
    k_prep<<<3128, 256, 0, stream>>>(Whh_f, Whh_b, Wih_f, Wih_b,
                                     bih_f, bhh_f, bih_b, bhh_b, W_out,
                                     WIHT2, BIAS, WV8, WL8, WOTP2);
    k_embed<<<2048, 320, 0, stream>>>(wid, fid, pid, ew, ef, epn, X);
    k_gemm<<<dim3(8, 512), 256, 0, stream>>>(X, WIHT2, BIAS, GX);
    k_lstm<<<128, 512, 0, stream>>>(WV8, (const uint4*)WL8, GX, h0, c0, HS);
    k_feats<<<4096, 384, 0, stream>>>((const unsigned int*)HS, (const uint4*)WOTP2, b_out, F);
    k_viterbi<<<64, 64, 0, stream>>>(F, trans, (float*)d_out);
}

// Round 15
// 1179.209 us; speedup vs baseline: 1.4185x; 1.2412x over previous
//
#include <hip/hip_runtime.h>
#include <hip/hip_bf16.h>
#include <hip/hip_fp16.h>
#include <math.h>

#define BB 64
#define SS 512
#define TT 48
#define EE 300
#define EP 320   // E padded
#define HH 256
#define G4 1024  // 4*H
#define NG 2048  // both directions
#define NEGV -10000.0f
#define SWQ (0.30f / 127.0f)   // Whh i8 scale

// k_lstm i8 weights per dir: 128 uints/thread (16 cols x 8 k-quads)
//   planes 0..63  (cols 0..7)  -> VGPR pin (64 regs)  [proven: granted 88, no spill]
//   planes 64..127 (cols 8..15) -> LDS 16 uint4-groups (128 KB)
#define NWV 65536    // 2*64*512 uints
#define NWL 65536    // 2*16*512*4 uints

// DPP: quad_perm xor1=0xB1, xor2=0x4E, rot[1,2,3,0]=0x39; row_half_mirror=0x141
#define DPP0(x, ctrl) __builtin_amdgcn_update_dpp(0, (int)(x), (ctrl), 0xf, 0xf, false)

typedef _Float16 f16x8 __attribute__((ext_vector_type(8)));
typedef float f32x4 __attribute__((ext_vector_type(4)));

__device__ __forceinline__ float sigf(float x) { return 1.0f / (1.0f + __expf(-x)); }
__device__ __forceinline__ float tanhf_(float x) {
    float e = __expf(2.0f * x);
    return 1.0f - 2.0f / (e + 1.0f);
}

__device__ __forceinline__ int dot4(unsigned int h, unsigned int w, int acc) {
#if __has_builtin(__builtin_amdgcn_sdot4)
    return __builtin_amdgcn_sdot4((int)h, (int)w, acc, false);
#else
    acc += (int)(signed char)(h)       * (int)(signed char)(w);
    acc += (int)(signed char)(h >> 8)  * (int)(signed char)(w >> 8);
    acc += (int)(signed char)(h >> 16) * (int)(signed char)(w >> 16);
    acc += (int)(signed char)(h >> 24) * (int)(signed char)(w >> 24);
    return acc;
#endif
}

__device__ __forceinline__ float dot2u(unsigned int h, unsigned int w, float acc) {
#if __has_builtin(__builtin_amdgcn_fdot2)
    typedef _Float16 h2v __attribute__((ext_vector_type(2)));
    union { unsigned int u; h2v v; } H, W;
    H.u = h; W.u = w;
    return __builtin_amdgcn_fdot2(H.v, W.v, acc, false);
#else
    __half2 hh = *(__half2*)&h, ww = *(__half2*)&w;
    float2 hf = __half22float2(hh), wf = __half22float2(ww);
    return acc + hf.x * wf.x + hf.y * wf.y;
#endif
}

__device__ __forceinline__ unsigned int packh2(float lo, float hi) {
    union { __half2 h; unsigned int u; } p;
    p.h = __floats2half2_rn(lo, hi);
    return p.u;
}

__device__ __forceinline__ unsigned int q8(float x) {
    int q = __float2int_rn(fminf(fmaxf(x, -127.0f), 127.0f));
    return (unsigned int)(q & 0xff);
}

// ---------------- prep + embed (merged, one dispatch) ----------------
// blocks [0, PREP_BLOCKS): weight prep, linear i = bid*320 + tid
// blocks [PREP_BLOCKS, +2048): embedding gather, 16 sb-rows per block
// Gate-interleaved col order: col c = 4j+qg <-> source row qg*256+j
// WIHT2: [2048 n][320 k] fp16 (n-major WihT, permuted cols, zero-padded K)
// BIAS:  [2048] fp32 (permuted)
// WV8:   [dir][64][512] uint (i8x4; plane p: lc=p>>3, kq=p&7)
// WL8:   [dir][16][512] uint4 (i8x4; group g: lc=8+(g>>1), kq=(g&1)*4+m)
// WOTP2: [64][48] uint4 (fp16 k-pairs of W_out^T, kp4-major)
#define PREP_BLOCKS 2503   // ceil(800768 / 320)
__global__ __launch_bounds__(320) void k_pe(
    const float* __restrict__ Whh_f, const float* __restrict__ Whh_b,
    const float* __restrict__ Wih_f, const float* __restrict__ Wih_b,
    const float* __restrict__ bih_f, const float* __restrict__ bhh_f,
    const float* __restrict__ bih_b, const float* __restrict__ bhh_b,
    const float* __restrict__ W_out,
    __half* __restrict__ WIHT2, float* __restrict__ BIAS,
    unsigned int* __restrict__ WV8, unsigned int* __restrict__ WL8,
    unsigned int* __restrict__ WOTP2,
    const int* __restrict__ wid, const int* __restrict__ fid,
    const int* __restrict__ pid,
    const float* __restrict__ ew, const float* __restrict__ ef,
    const float* __restrict__ ep, __half* __restrict__ X)
{
    if (blockIdx.x >= PREP_BLOCKS) {
        int t = threadIdx.x;
        int sb0 = (blockIdx.x - PREP_BLOCKS) * 16;
        #pragma unroll 4
        for (int it = 0; it < 16; it++) {
            int sb = sb0 + it;
            int s = sb >> 6, b = sb & 63;
            int w = wid[b * SS + s];
            int f = fid[b * SS + s];
            int p = pid[b * SS + s];
            float v;
            if (t < 200)      v = ew[w * 200 + t];
            else if (t < 250) v = ef[f * 50 + (t - 200)];
            else if (t < 300) v = ep[p * 50 + (t - 250)];
            else              v = 0.0f;
            X[(size_t)sb * EP + t] = __float2half(v);
        }
        return;
    }
    int i = blockIdx.x * 320 + threadIdx.x;
    const int NWIHT2 = NG * EP;    // 655360
    if (i < NWIHT2) {
        int n = i / EP, k = i % EP;
        int d = n >> 10, c = n & 1023;
        int row = (c & 3) * 256 + (c >> 2);
        const float* w = d ? Wih_b : Wih_f;
        WIHT2[i] = __float2half(k < EE ? w[row * EE + k] : 0.0f);
        return;
    }
    i -= NWIHT2;
    if (i < NG) {
        int d = i >> 10, c = i & 1023;
        int row = (c & 3) * 256 + (c >> 2);
        BIAS[i] = d ? (bih_b[row] + bhh_b[row]) : (bih_f[row] + bhh_f[row]);
        return;
    }
    i -= NG;
    if (i < NWV) {
        int d = i >> 15, rem = i & 32767;
        int p = rem >> 9, t = rem & 511;
        int G = t >> 3, r = t & 7;
        int lc = p >> 3, kq = p & 7;
        int col = 16 * G + lc;
        int row = (col & 3) * 256 + (col >> 2);
        int k0 = 32 * r + 4 * kq;
        const float* W = d ? Whh_b : Whh_f;
        unsigned int v = 0;
        #pragma unroll
        for (int bb = 0; bb < 4; bb++)
            v |= q8(W[row * HH + k0 + bb] * (1.0f / SWQ)) << (8 * bb);
        WV8[i] = v;
        return;
    }
    i -= NWV;
    if (i < NWL) {
        int d = i >> 15, rem = i & 32767;
        int g = rem >> 11, i3 = rem & 2047;
        int t = i3 >> 2, m = i3 & 3;
        int G = t >> 3, r = t & 7;
        int lc = 8 + (g >> 1), kq = (g & 1) * 4 + m;
        int col = 16 * G + lc;
        int row = (col & 3) * 256 + (col >> 2);
        int k0 = 32 * r + 4 * kq;
        const float* W = d ? Whh_b : Whh_f;
        unsigned int v = 0;
        #pragma unroll
        for (int bb = 0; bb < 4; bb++)
            v |= q8(W[row * HH + k0 + bb] * (1.0f / SWQ)) << (8 * bb);
        WL8[i] = v;
        return;
    }
    i -= NWL;
    if (i < 48 * 256) {   // 12288 uints
        int u4 = i >> 2;
        int kp4 = u4 / 48, t = u4 % 48;
        int kp = kp4 * 4 + (i & 3);
        WOTP2[i] = packh2(W_out[t * 512 + 2 * kp], W_out[t * 512 + 2 * kp + 1]);
        return;
    }
}

// ---------------- input GEMM: MFMA 16x16x32 f16, global-direct frags -----
// grid (8, 512), 256 thr = 4 waves; wave computes 64(m) x 64(n) tile.
// A/B share the same (lane-group,elem)->k storage mapping => any k-perm
// vs HW mapping cancels. C/D mapping: col=lane&15, row=(lane>>4)*4+reg.
__global__ __launch_bounds__(256) void k_gemm(
    const __half* __restrict__ X, const __half* __restrict__ WT,
    const float* __restrict__ BIAS, __half* __restrict__ GX)
{
    int tid = threadIdx.x;
    int l = tid & 63, wn = tid >> 6;
    int m0 = blockIdx.y * 64, nb = blockIdx.x * 256 + wn * 64;
    int lr = l & 15, lg = l >> 4;

    f32x4 acc[16];
    #pragma unroll
    for (int i = 0; i < 16; i++) acc[i] = (f32x4){0.0f, 0.0f, 0.0f, 0.0f};

    const __half* ab = X  + (size_t)(m0 + lr) * EP + lg * 8;
    const __half* bb = WT + (size_t)(nb + lr) * EP + lg * 8;
    for (int kc = 0; kc < 10; kc++) {
        f16x8 af[4], bf[4];
        #pragma unroll
        for (int mi = 0; mi < 4; mi++)
            af[mi] = *(const f16x8*)(ab + (size_t)mi * 16 * EP + kc * 32);
        #pragma unroll
        for (int nj = 0; nj < 4; nj++)
            bf[nj] = *(const f16x8*)(bb + (size_t)nj * 16 * EP + kc * 32);
        #pragma unroll
        for (int mi = 0; mi < 4; mi++)
            #pragma unroll
            for (int nj = 0; nj < 4; nj++)
                acc[mi * 4 + nj] = __builtin_amdgcn_mfma_f32_16x16x32_f16(
                    af[mi], bf[nj], acc[mi * 4 + nj], 0, 0, 0);
    }
    #pragma unroll
    for (int nj = 0; nj < 4; nj++) {
        float bias = BIAS[nb + nj * 16 + lr];
        #pragma unroll
        for (int mi = 0; mi < 4; mi++) {
            f32x4 a = acc[mi * 4 + nj];
            #pragma unroll
            for (int v = 0; v < 4; v++) {
                int m = m0 + mi * 16 + lg * 4 + v;
                GX[(size_t)m * NG + nb + nj * 16 + lr] = __float2half(a[v] + bias);
            }
        }
    }
}

// ---------------- recurrent LSTM: i8 resident, DPP reduce (r11 proven) ---
// 128 wgs x 512 thr. Octet G=t>>3 owns cols [16G,16G+16); lane r=t&7 owns
// k in [32r,32r+32). 64 weight-uints pinned in VGPRs + 64 in LDS (128 KB).
__global__ __launch_bounds__(512, 1) void k_lstm(
    const unsigned int* __restrict__ WV8, const uint4* __restrict__ WL8,
    const __half* __restrict__ GX, const float* __restrict__ h0,
    const float* __restrict__ c0, __half* __restrict__ HS)
{
    __shared__ uint4 LW[16 * 512];          // 128 KB i8 weights
    __shared__ unsigned int h8[2][64];      // packed i8 h
    int wg = blockIdx.x; int dir = wg >> 6, b = wg & 63;
    int t = threadIdx.x;
    int G = t >> 3, r = t & 7, rp = r & 3;

    const uint4* wl = WL8 + (size_t)dir * (16 * 512);
    #pragma unroll
    for (int g = 0; g < 16; g++) LW[g * 512 + t] = wl[g * 512 + t];

    const unsigned int* wv = WV8 + (size_t)dir * (64 * 512);
    unsigned int WR[64];
    #pragma unroll
    for (int p = 0; p < 64; p++) {
        unsigned int tmp = wv[p * 512 + t];
        asm volatile("v_mov_b32 %0, %1" : "=v"(WR[p]) : "v"(tmp));
    }

    size_t sbase = (size_t)dir * BB * HH + b * HH;
    float c = c0[sbase + 4 * G + rp];
    if (t < 64) {
        unsigned int v = 0;
        #pragma unroll
        for (int u = 0; u < 4; u++)
            v |= q8(h0[sbase + 4 * t + u] * (127.0f / 5.0f)) << (8 * u);
        h8[0][t] = v;
    }
    __syncthreads();

    const __half* gxbase = GX + (dir << 10);
    int s0 = dir ? (SS - 1) : 0;
    int unit = 4 * G + rp;
    uint2 gx = *(const uint2*)(gxbase + (size_t)(s0 * BB + b) * NG + 4 * unit);

    int cur = 0;
    for (int tt = 0; tt < SS; tt++) {
        int s  = dir ? (SS - 1 - tt) : tt;
        int tn = (tt + 1 < SS) ? (tt + 1) : tt;
        int sn = dir ? (SS - 1 - tn) : tn;
        uint2 gx_n = *(const uint2*)(gxbase + (size_t)(sn * BB + b) * NG + 4 * unit);

        uint4 hA = *(const uint4*)&h8[cur][8 * r];
        uint4 hB = *(const uint4*)&h8[cur][8 * r + 4];
        unsigned int hr[8] = { hA.x, hA.y, hA.z, hA.w, hB.x, hB.y, hB.z, hB.w };

        int acc[16];
        #pragma unroll
        for (int m = 0; m < 16; m++) acc[m] = 0;
        #pragma unroll
        for (int p = 0; p < 64; p++)
            acc[p >> 3] = dot4(hr[p & 7], WR[p], acc[p >> 3]);
        #pragma unroll
        for (int g = 0; g < 16; g++) {
            uint4 w = LW[g * 512 + t];
            const int lc = 8 + (g >> 1), kq0 = (g & 1) * 4;
            acc[lc] = dot4(hr[kq0 + 0], w.x, acc[lc]);
            acc[lc] = dot4(hr[kq0 + 1], w.y, acc[lc]);
            acc[lc] = dot4(hr[kq0 + 2], w.z, acc[lc]);
            acc[lc] = dot4(hr[kq0 + 3], w.w, acc[lc]);
        }

        // stage A: fold pairs r <-> 7-r (row_half_mirror)
        #pragma unroll
        for (int m = 0; m < 16; m++) acc[m] += DPP0(acc[m], 0x141);
        // stage B (xor2 quad_perm): keep 8 cols
        bool keep2 = (r & 2) == 0;
        int b8v[8];
        #pragma unroll
        for (int m = 0; m < 8; m++) {
            int send = keep2 ? acc[8 + m] : acc[m];
            int got  = DPP0(send, 0x4E);
            b8v[m] = (keep2 ? acc[m] : acc[8 + m]) + got;
        }
        // stage C (xor1): lane r holds cols 4(r&3)..+3
        bool keep1 = (r & 1) == 0;
        int f4v[4];
        #pragma unroll
        for (int m = 0; m < 4; m++) {
            int send = keep1 ? b8v[4 + m] : b8v[m];
            int got  = DPP0(send, 0xB1);
            f4v[m] = (keep1 ? b8v[m] : b8v[4 + m]) + got;
        }

        float st = SWQ * ((tt == 0) ? (5.0f / 127.0f) : (1.0f / 127.0f));
        __half2 g01 = *(__half2*)&gx.x;  float2 f01 = __half22float2(g01);
        __half2 g23 = *(__half2*)&gx.y;  float2 f23 = __half22float2(g23);
        float pi = f01.x + st * (float)f4v[0];
        float pf = f01.y + st * (float)f4v[1];
        float pg = f23.x + st * (float)f4v[2];
        float po = f23.y + st * (float)f4v[3];
        c = sigf(pf) * c + sigf(pi) * tanhf_(pg);
        float h = sigf(po) * tanhf_(c);

        unsigned int hv = q8(h * 127.0f) << (8 * rp);
        hv |= (unsigned int)DPP0(hv, 0xB1);
        hv |= (unsigned int)DPP0(hv, 0x4E);
        if (r == 0) h8[cur ^ 1][G] = hv;

        float hnx = __int_as_float(DPP0(__float_as_int(h), 0x39));
        if (r == 0 || r == 2)
            *(unsigned int*)(HS + (size_t)(s * BB + b) * 512 + (dir << 8) + 4 * G + r)
                = packh2(h, hnx);

        __syncthreads();
        cur ^= 1;
        gx = gx_n;
    }
}

// ---------------- feats: fp16 dot2, coalesced W_out^T ---------------------
__global__ __launch_bounds__(384) void k_feats(
    const unsigned int* __restrict__ HSU, const uint4* __restrict__ W2,
    const float* __restrict__ b_out, float* __restrict__ F)
{
    __shared__ unsigned int rl_u[8 * 256];
    int sb0 = blockIdx.x * 8;
    int tid = threadIdx.x;
    for (int i = tid; i < 512; i += 384) {
        int row = i >> 6, u4c = i & 63;
        uint4 v = *(const uint4*)(HSU + (size_t)(sb0 + row) * 256 + u4c * 4);
        *(uint4*)&rl_u[row * 256 + u4c * 4] = v;
    }
    __syncthreads();
    int rr = tid / TT, t = tid % TT;
    float acc = b_out[t];
    #pragma unroll 8
    for (int kp4 = 0; kp4 < 64; kp4++) {
        uint4 ru = *(const uint4*)&rl_u[rr * 256 + kp4 * 4];
        uint4 wu = W2[kp4 * 48 + t];
        acc = dot2u(ru.x, wu.x, acc);
        acc = dot2u(ru.y, wu.y, acc);
        acc = dot2u(ru.z, wu.z, acc);
        acc = dot2u(ru.w, wu.w, acc);
    }
    F[(size_t)(sb0 + rr) * TT + t] = acc;
}

// ---------------- Viterbi: 4 waves/batch, trans in regs, chunked prev ----
// 64 blocks x 256 thr. Thread (nx=tid%48, pc=tid/48<4) scans prev chunk
// [12pc,12pc+12) with its transitions column in 12 REGISTERS (step-
// invariant) and fv read as 3x b128. Tie-break preserves argmax-first:
// first-max within chunk; strictly-greater across ascending chunks.
__global__ __launch_bounds__(256) void k_viterbi(
    const float* __restrict__ F, const float* __restrict__ trans,
    float* __restrict__ out)
{
    int b = blockIdx.x;
    int tid = threadIdx.x;
    int nx = tid % TT, pc = tid / TT;   // pc<4 active (tid<192)
    __shared__ __align__(16) float fv[TT];
    __shared__ float red[4][TT];
    __shared__ unsigned char redi[4][TT];
    __shared__ unsigned char bp[SS * TT];
    __shared__ unsigned char path[SS];

    float treg[12];
    if (pc < 4) {
        int p0 = pc * 12;
        float4 t0 = *(const float4*)(trans + nx * TT + p0);
        float4 t1 = *(const float4*)(trans + nx * TT + p0 + 4);
        float4 t2 = *(const float4*)(trans + nx * TT + p0 + 8);
        treg[0] = t0.x; treg[1]  = t0.y; treg[2]  = t0.z; treg[3]  = t0.w;
        treg[4] = t1.x; treg[5]  = t1.y; treg[6]  = t1.z; treg[7]  = t1.w;
        treg[8] = t2.x; treg[9]  = t2.y; treg[10] = t2.z; treg[11] = t2.w;
    }
    if (tid < TT) fv[tid] = NEGV;
    __syncthreads();

    float f0 = (tid < TT) ? F[(size_t)(0 * BB + b) * TT + tid] : 0.0f;
    float f1 = (tid < TT) ? F[(size_t)(1 * BB + b) * TT + tid] : 0.0f;
    for (int s = 0; s < SS; s++) {
        float f2 = (tid < TT && s + 2 < SS)
                 ? F[(size_t)((s + 2) * BB + b) * TT + tid] : 0.0f;
        if (pc < 4) {
            int p0 = pc * 12;
            float4 v0 = *(const float4*)&fv[p0];
            float4 v1 = *(const float4*)&fv[p0 + 4];
            float4 v2 = *(const float4*)&fv[p0 + 8];
            float fvv[12] = { v0.x, v0.y, v0.z, v0.w,
                              v1.x, v1.y, v1.z, v1.w,
                              v2.x, v2.y, v2.z, v2.w };
            float best = -1e30f; int bi = 0;
            #pragma unroll
            for (int k = 0; k < 12; k++) {
                float sc = fvv[k] + treg[k];
                if (sc > best) { best = sc; bi = p0 + k; }
            }
            red[pc][nx] = best;
            redi[pc][nx] = (unsigned char)bi;
        }
        __syncthreads();
        if (tid < TT) {
            float best = red[0][tid]; int bi = redi[0][tid];
            #pragma unroll
            for (int q = 1; q < 4; q++) {
                float v = red[q][tid];
                if (v > best) { best = v; bi = redi[q][tid]; }
            }
            bp[s * TT + tid] = (unsigned char)bi;
            fv[tid] = best + f0;
        }
        __syncthreads();
        f0 = f1; f1 = f2;
    }
    if (tid == 0) {
        float best = fv[0]; int bi = 0;
        for (int i = 1; i < TT; i++) if (fv[i] > best) { best = fv[i]; bi = i; }
        out[b] = best;
        int tag = bi;
        path[SS - 1] = (unsigned char)tag;
        for (int jj = SS - 2; jj >= 0; jj--) {
            tag = bp[(jj + 1) * TT + tag];
            path[jj] = (unsigned char)tag;
        }
    }
    __syncthreads();
    for (int jj = tid; jj < SS; jj += 256)
        out[BB + (size_t)b * SS + jj] = (float)path[jj];
}

extern "C" void kernel_launch(void* const* d_in, const int* in_sizes, int n_in,
                              void* d_out, int out_size, void* d_ws, size_t ws_size,
                              hipStream_t stream) {
    const int*   wid    = (const int*)d_in[0];
    const int*   fid    = (const int*)d_in[1];
    const int*   pid    = (const int*)d_in[2];
    const float* ew     = (const float*)d_in[3];
    const float* ef     = (const float*)d_in[4];
    const float* epn    = (const float*)d_in[5];
    const float* Wih_f  = (const float*)d_in[6];
    const float* Whh_f  = (const float*)d_in[7];
    const float* bih_f  = (const float*)d_in[8];
    const float* bhh_f  = (const float*)d_in[9];
    const float* Wih_b  = (const float*)d_in[10];
    const float* Whh_b  = (const float*)d_in[11];
    const float* bih_b  = (const float*)d_in[12];
    const float* bhh_b  = (const float*)d_in[13];
    const float* h0     = (const float*)d_in[14];
    const float* c0     = (const float*)d_in[15];
    const float* W_out  = (const float*)d_in[16];
    const float* b_out  = (const float*)d_in[17];
    const float* trans  = (const float*)d_in[18];

    char* p = (char*)d_ws;
    auto alloc = [&](size_t bytes) { char* r = p; p += (bytes + 255) & ~(size_t)255; return r; };
    __half*       X      = (__half*)alloc((size_t)32768 * EP * 2);       //  21.0 MB
    __half*       GX     = (__half*)alloc((size_t)32768 * NG * 2);       // 134.2 MB
    __half*       HS     = (__half*)alloc((size_t)32768 * 512 * 2);      //  33.6 MB
    unsigned int* WV8    = (unsigned int*)alloc((size_t)NWV * 4);        //  256 KB
    unsigned int* WL8    = (unsigned int*)alloc((size_t)NWL * 4);        //  256 KB
    __half*       WIHT2  = (__half*)alloc((size_t)NG * EP * 2);          //   1.3 MB
    float*        BIAS   = (float*)alloc((size_t)NG * 4);                //   8 KB
    unsigned int* WOTP2  = (unsigned int*)alloc((size_t)48 * 256 * 4);   //  48 KB
    float*        F      = (float*)alloc((size_t)32768 * TT * 4);        //   6.3 MB

    // merged prep (2503 blocks, 800768 elems) + embed (2048 blocks)
    k_pe<<<PREP_BLOCKS + 2048, 320, 0, stream>>>(
        Whh_f, Whh_b, Wih_f, Wih_b, bih_f, bhh_f, bih_b, bhh_b, W_out,
        WIHT2, BIAS, WV8, WL8, WOTP2,
        wid, fid, pid, ew, ef, epn, X);
    k_gemm<<<dim3(8, 512), 256, 0, stream>>>(X, WIHT2, BIAS, GX);
    k_lstm<<<128, 512, 0, stream>>>(WV8, (const uint4*)WL8, GX, h0, c0, HS);
    k_feats<<<4096, 384, 0, stream>>>((const unsigned int*)HS, (const uint4*)WOTP2, b_out, F);
    k_viterbi<<<64, 256, 0, stream>>>(F, trans, (float*)d_out);
}